// Round 6
// baseline (94.471 us; speedup 1.0000x reference)
//
#include <hip/hip_runtime.h>
#include <math.h>

#define NFEAT 768
#define NT    128   // each thread processes TWO batch elements (dual-element ILP)

typedef float f2 __attribute__((ext_vector_type(2)));

// GF2-linear LDS swizzle (bijective; verified rank-4 bank spread for all patterns)
__device__ __forceinline__ int swz(int j){ return j ^ (j >> 4) ^ ((j >> 2) & 0xC); }

// Composite of the CNOT ring CNOT(0,1),...,CNOT(9,0): s_after[j] = s_before[perm(j)].
__device__ __forceinline__ int cnot_perm(int j){
  int i = j;
  i ^= ((i >> 0) & 1) << 9;
  i ^= ((i >> 1) & 1) << 0;
  i ^= ((i >> 2) & 1) << 1;
  i ^= ((i >> 3) & 1) << 2;
  i ^= ((i >> 4) & 1) << 3;
  i ^= ((i >> 5) & 1) << 4;
  i ^= ((i >> 6) & 1) << 5;
  i ^= ((i >> 7) & 1) << 6;
  i ^= ((i >> 8) & 1) << 7;
  i ^= ((i >> 9) & 1) << 8;
  return i;
}

// packed 64-bit lane shuffle (two components move together)
__device__ __forceinline__ f2 shfl_xor_f2(f2 v, int m){
  double d = __builtin_bit_cast(double, v);
  d = __shfl_xor(d, m);
  return __builtin_bit_cast(f2, d);
}

// ---- packed-f32 complex primitives (VOP3P) ----
__device__ __forceinline__ f2 pk_cmul(f2 s, f2 v){
  f2 d;
  asm("v_pk_mul_f32 %0, %1, %2 op_sel:[0,0] op_sel_hi:[0,1]\n\t"
      "v_pk_fma_f32 %0, %1, %2, %0 op_sel:[1,1,0] op_sel_hi:[1,0,1] neg_lo:[0,1,0]"
      : "=&v"(d) : "v"(s), "v"(v));
  return d;
}
__device__ __forceinline__ f2 pk_cfma(f2 s, f2 v, f2 acc){
  f2 d;
  asm("v_pk_fma_f32 %0, %2, %3, %1 op_sel:[0,0,0] op_sel_hi:[0,1,1]\n\t"
      "v_pk_fma_f32 %0, %2, %3, %0 op_sel:[1,1,0] op_sel_hi:[1,0,1] neg_lo:[0,1,0]"
      : "=&v"(d) : "v"(acc), "v"(s), "v"(v));
  return d;
}
// d = acc + (a.r*b.i, -a.i*b.r)
__device__ __forceinline__ f2 pk_cross(f2 a, f2 b, f2 acc){
  f2 d;
  asm("v_pk_fma_f32 %0, %2, %3, %1 op_sel:[0,1,0] op_sel_hi:[1,0,1] neg_hi:[1,0,0]"
      : "=&v"(d) : "v"(acc), "v"(a), "v"(b));
  return d;
}
// RY with cs=(c,s): a' = c*a - s*b ; b' = s*a + c*b
__device__ __forceinline__ void pk_ry(f2 cs, f2& a, f2& b){
  f2 t1, t2, na, nb;
  asm("v_pk_mul_f32 %0, %2, %3 op_sel:[1,0] op_sel_hi:[1,1] neg_lo:[1,0] neg_hi:[1,0]\n\t"
      "v_pk_mul_f32 %1, %2, %4 op_sel:[1,0] op_sel_hi:[1,1]"
      : "=&v"(t1), "=&v"(t2) : "v"(cs), "v"(b), "v"(a));
  asm("v_pk_fma_f32 %0, %2, %3, %4 op_sel:[0,0,0] op_sel_hi:[0,1,1]\n\t"
      "v_pk_fma_f32 %1, %2, %5, %6 op_sel:[0,0,0] op_sel_hi:[0,1,1]"
      : "=&v"(na), "=&v"(nb) : "v"(cs), "v"(a), "v"(t1), "v"(b), "v"(t2));
  a = na; b = nb;
}
__device__ __forceinline__ void pk_u(f2 u00, f2 u01, f2 u10, f2 u11, f2& a, f2& b){
  const f2 na = pk_cfma(u01, b, pk_cmul(u00, a));
  const f2 nb = pk_cfma(u11, b, pk_cmul(u10, a));
  a = na; b = nb;
}
// DIF butterfly: a' = a+b ; b' = (a-b)*tw
__device__ __forceinline__ void bfly(f2& a, f2& b, f2 tw){
  const f2 u = a + b;
  const f2 v = a - b;
  a = u;
  b = pk_cmul(tw, v);
}

template<int S>
__device__ __forceinline__ int baseS(int t){ return (t & ((1<<S)-1)) | ((t >> S) << (S+3)); }

template<int S>
__device__ __forceinline__ void rd8(const f2* bb, int a0, f2* xv){
  #pragma unroll
  for (int m = 0; m < 8; ++m) xv[m] = bb[a0 ^ swz(m << S)];
}
template<int S>
__device__ __forceinline__ void wr8(f2* bb, int a0, const f2* xv){
  #pragma unroll
  for (int m = 0; m < 8; ++m) bb[a0 ^ swz(m << S)] = xv[m];
}

__device__ __forceinline__ void apply3U(f2* xv, const f2* g2, int Q){
  { const f2 u00=g2[4*Q+0], u01=g2[4*Q+1], u10=g2[4*Q+2], u11=g2[4*Q+3];
    pk_u(u00,u01,u10,u11,xv[0],xv[4]); pk_u(u00,u01,u10,u11,xv[1],xv[5]);
    pk_u(u00,u01,u10,u11,xv[2],xv[6]); pk_u(u00,u01,u10,u11,xv[3],xv[7]); }
  { const f2 u00=g2[4*Q+4], u01=g2[4*Q+5], u10=g2[4*Q+6], u11=g2[4*Q+7];
    pk_u(u00,u01,u10,u11,xv[0],xv[2]); pk_u(u00,u01,u10,u11,xv[1],xv[3]);
    pk_u(u00,u01,u10,u11,xv[4],xv[6]); pk_u(u00,u01,u10,u11,xv[5],xv[7]); }
  { const f2 u00=g2[4*Q+8], u01=g2[4*Q+9], u10=g2[4*Q+10], u11=g2[4*Q+11];
    pk_u(u00,u01,u10,u11,xv[0],xv[1]); pk_u(u00,u01,u10,u11,xv[2],xv[3]);
    pk_u(u00,u01,u10,u11,xv[4],xv[5]); pk_u(u00,u01,u10,u11,xv[6],xv[7]); }
}

__device__ __forceinline__ void apply3RY(f2* xv, const f2* gry, int Q){
  { const f2 cs = gry[Q];
    pk_ry(cs,xv[0],xv[4]); pk_ry(cs,xv[1],xv[5]); pk_ry(cs,xv[2],xv[6]); pk_ry(cs,xv[3],xv[7]); }
  { const f2 cs = gry[Q+1];
    pk_ry(cs,xv[0],xv[2]); pk_ry(cs,xv[1],xv[3]); pk_ry(cs,xv[4],xv[6]); pk_ry(cs,xv[5],xv[7]); }
  { const f2 cs = gry[Q+2];
    pk_ry(cs,xv[0],xv[1]); pk_ry(cs,xv[2],xv[3]); pk_ry(cs,xv[4],xv[5]); pk_ry(cs,xv[6],xv[7]); }
}

__device__ __forceinline__ void fft8_stages(f2* xv, const f2 tA, const f2 tAE, const f2 tB, const f2 tC){
  const f2 itA  = {-tA.y,  tA.x};
  const f2 itAE = {-tAE.y, tAE.x};
  bfly(xv[0], xv[4], tA);  bfly(xv[1], xv[5], tAE);
  bfly(xv[2], xv[6], itA); bfly(xv[3], xv[7], itAE);
  const f2 itB = {-tB.y, tB.x};
  bfly(xv[0], xv[2], tB);  bfly(xv[1], xv[3], itB);
  bfly(xv[4], xv[6], tB);  bfly(xv[5], xv[7], itB);
  bfly(xv[0], xv[1], tC);  bfly(xv[2], xv[3], tC);
  bfly(xv[4], xv[5], tC);  bfly(xv[6], xv[7], tC);
}

template<int MASK>
__device__ __forceinline__ void pairsum(const f2* z, float& xr, float& xi){
  f2 rp = {0.f, 0.f}, ip = {0.f, 0.f};
  #pragma unroll
  for (int m = 0; m < 8; ++m){
    if ((m & MASK) == 0){
      rp = z[m]*z[m|MASK] + rp;
      ip = pk_cross(z[m], z[m|MASK], ip);
    }
  }
  xr = rp.x + rp.y; xi = ip.x + ip.y;
}

__global__ void gate_prep(const float* __restrict__ w, float* __restrict__ gt){
  const int t = threadIdx.x;
  if (t >= 10) return;
  const float ha = 0.5f*w[t*4+0], hb = 0.5f*w[t*4+1];
  const float hg = 0.5f*w[t*4+2], hd = 0.5f*w[t*4+3];
  const float ca = cosf(ha), sa = sinf(ha);
  const float cb = cosf(hb), sb = sinf(hb);
  const float cg = cosf(hg), sg = sinf(hg);
  const float m00r = cb*ca, m00i =  sb*sa;
  const float m01r = -sb*ca, m01i = -cb*sa;
  const float m10r =  sb*ca, m10i = -cb*sa;
  const float m11r = cb*ca,  m11i = -sb*sa;
  gt[8*t+0] = cg*m00r + sg*m00i;  gt[8*t+1] = cg*m00i - sg*m00r;
  gt[8*t+2] = cg*m01r + sg*m01i;  gt[8*t+3] = cg*m01i - sg*m01r;
  gt[8*t+4] = cg*m10r - sg*m10i;  gt[8*t+5] = cg*m10i + sg*m10r;
  gt[8*t+6] = cg*m11r - sg*m11i;  gt[8*t+7] = cg*m11i + sg*m11r;
  gt[80+2*t] = cosf(hd); gt[81+2*t] = sinf(hd);
}

__global__ void __launch_bounds__(NT, 4)
qqk_kernel(const float* __restrict__ x, const float* __restrict__ gt,
           float* __restrict__ out)
{
  __shared__ f2 buf[2][1024];   // state of elem A / elem B (swizzled); later 12x33 rows
  __shared__ f2 wredS[2];       // per-wave packed (A,B) norm partials
  __shared__ f2 wzS[2][7];      // per-wave packed WH partials

  const int b    = blockIdx.x;
  const int t    = threadIdx.x;
  const int wave = t >> 6;
  const int lane = t & 63;
  const f2* g2  = (const f2*)gt;
  const f2* gry = (const f2*)(gt + 80);
  f2* b0 = buf[0];
  f2* b1 = buf[1];
  const int st = swz(t);

  // ---- load both elements (6 cols + 2 zero pads) + packed norm ----
  f2 xa[8], xb[8];
  const float* xA = x + (size_t)(2*b) * NFEAT;
  const float* xB = xA + NFEAT;
  f2 ss = {0.f, 0.f};
  #pragma unroll
  for (int m = 0; m < 6; ++m){
    const float va = xA[t + 128*m], vb = xB[t + 128*m];
    xa[m] = f2{va, 0.f}; xb[m] = f2{vb, 0.f};
    ss += f2{va*va, vb*vb};
  }
  xa[6] = f2{0.f,0.f}; xa[7] = f2{0.f,0.f};
  xb[6] = f2{0.f,0.f}; xb[7] = f2{0.f,0.f};
  #pragma unroll
  for (int m = 1; m < 64; m <<= 1) ss += shfl_xor_f2(ss, m);
  if (lane == 0) wredS[wave] = ss;
  __syncthreads();
  const f2 tot = wredS[0] + wredS[1];
  const float invA = 1.0f / fmaxf(sqrtf(tot.x), 1e-8f);
  const float invB = 1.0f / fmaxf(sqrtf(tot.y), 1e-8f);
  #pragma unroll
  for (int m = 0; m < 6; ++m){ xa[m].x *= invA; xb[m].x *= invB; }

  // ---- gate pass 0 (qubits 0,1,2 = bits 9,8,7), fused with load ----
  apply3U(xa, g2, 0); apply3U(xb, g2, 0);
  wr8<7>(b0, st, xa); wr8<7>(b1, st, xb);
  __syncthreads();
  // ---- gate pass 1 (qubits 3,4,5) ----
  { const int a0 = swz(baseS<4>(t));
    rd8<4>(b0, a0, xa); rd8<4>(b1, a0, xb);
    apply3U(xa, g2, 3); apply3U(xb, g2, 3);
    wr8<4>(b0, a0, xa); wr8<4>(b1, a0, xb); }
  __syncthreads();
  // ---- gate pass 2 (qubits 6,7,8) ----
  { const int a0 = swz(baseS<1>(t));
    rd8<1>(b0, a0, xa); rd8<1>(b1, a0, xb);
    apply3U(xa, g2, 6); apply3U(xb, g2, 6);
    wr8<1>(b0, a0, xa); wr8<1>(b1, a0, xb); }
  __syncthreads();
  // ---- gate pass 3 (qubit 9, bit 0) ----
  { const int a0 = swz(t << 3);
    rd8<0>(b0, a0, xa); rd8<0>(b1, a0, xb);
    const f2 u00=g2[36], u01=g2[37], u10=g2[38], u11=g2[39];
    pk_u(u00,u01,u10,u11,xa[0],xa[1]); pk_u(u00,u01,u10,u11,xa[2],xa[3]);
    pk_u(u00,u01,u10,u11,xa[4],xa[5]); pk_u(u00,u01,u10,u11,xa[6],xa[7]);
    pk_u(u00,u01,u10,u11,xb[0],xb[1]); pk_u(u00,u01,u10,u11,xb[2],xb[3]);
    pk_u(u00,u01,u10,u11,xb[4],xb[5]); pk_u(u00,u01,u10,u11,xb[6],xb[7]);
    wr8<0>(b0, a0, xa); wr8<0>(b1, a0, xb); }
  __syncthreads();

  // ---- CNOT-ring gather + RY qubits 0,1,2 ----
  { const int pt = swz(cnot_perm(t));
    #pragma unroll
    for (int m = 0; m < 8; ++m){
      const int ad = pt ^ swz(cnot_perm(m << 7));
      xa[m] = b0[ad]; xb[m] = b1[ad];
    }
    __syncthreads();            // all gather reads done before overwrite
    apply3RY(xa, gry, 0); apply3RY(xb, gry, 0);
    wr8<7>(b0, st, xa); wr8<7>(b1, st, xb); }
  __syncthreads();
  // ---- RY qubits 3,4,5 ----
  { const int a0 = swz(baseS<4>(t));
    rd8<4>(b0, a0, xa); rd8<4>(b1, a0, xb);
    apply3RY(xa, gry, 3); apply3RY(xb, gry, 3);
    wr8<4>(b0, a0, xa); wr8<4>(b1, a0, xb); }
  __syncthreads();
  // ---- RY qubits 6,7,8 ----
  { const int a0 = swz(baseS<1>(t));
    rd8<1>(b0, a0, xa); rd8<1>(b1, a0, xb);
    apply3RY(xa, gry, 6); apply3RY(xb, gry, 6);
    wr8<1>(b0, a0, xa); wr8<1>(b1, a0, xb); }
  __syncthreads();
  // ---- RY qubit 9 ----
  { const int a0 = swz(t << 3);
    rd8<0>(b0, a0, xa); rd8<0>(b1, a0, xb);
    const f2 cs = gry[9];
    pk_ry(cs,xa[0],xa[1]); pk_ry(cs,xa[2],xa[3]); pk_ry(cs,xa[4],xa[5]); pk_ry(cs,xa[6],xa[7]);
    pk_ry(cs,xb[0],xb[1]); pk_ry(cs,xb[2],xb[3]); pk_ry(cs,xb[4],xb[5]); pk_ry(cs,xb[6],xb[7]);
    wr8<0>(b0, a0, xa); wr8<0>(b1, a0, xb); }
  __syncthreads();

  const float c45 = 0.70710678118f;
  // ---- FFT pass 0: stages span 512,256,128 (twiddles shared by A,B) ----
  { rd8<7>(b0, st, xa); rd8<7>(b1, st, xb);
    float sa, ca; __sincosf((float)t * 6.13592315154256e-3f, &sa, &ca);   // T(t)
    const f2 tA  = {ca, sa};
    const f2 tAE = {c45*(ca - sa), c45*(ca + sa)};
    const f2 tB  = pk_cmul(tA, tA);
    const f2 tC  = pk_cmul(tB, tB);
    fft8_stages(xa, tA, tAE, tB, tC);
    fft8_stages(xb, tA, tAE, tB, tC);
    wr8<7>(b0, st, xa); wr8<7>(b1, st, xb); }
  __syncthreads();
  // ---- FFT pass 1: spans 64,32,16 ----
  { const int a0 = swz(baseS<4>(t));
    rd8<4>(b0, a0, xa); rd8<4>(b1, a0, xb);
    const int l = t & 15;
    float sa, ca; __sincosf((float)l * 4.90873852123e-2f, &sa, &ca);      // T(8l)
    const f2 tA  = {ca, sa};
    const f2 tAE = {c45*(ca - sa), c45*(ca + sa)};
    const f2 tB  = pk_cmul(tA, tA);
    const f2 tC  = pk_cmul(tB, tB);
    fft8_stages(xa, tA, tAE, tB, tC);
    fft8_stages(xb, tA, tAE, tB, tC);
    wr8<4>(b0, a0, xa); wr8<4>(b1, a0, xb); }
  __syncthreads();
  // ---- FFT pass 2: spans 8,4,2 ----
  { const int a0 = swz(baseS<1>(t));
    rd8<1>(b0, a0, xa); rd8<1>(b1, a0, xb);
    const float c22 = 0.92387953251f, s22 = 0.38268343236f;
    const bool l = (t & 1);
    const f2 tA  = { l ? c22 : 1.f, l ? s22 : 0.f };
    const f2 tAE = { l ? s22 : c45, l ? c22 : c45 };
    const f2 tB  = { l ? c45 : 1.f, l ? c45 : 0.f };
    const f2 tC  = { l ? 0.f : 1.f, l ? 1.f : 0.f };
    fft8_stages(xa, tA, tAE, tB, tC);
    fft8_stages(xb, tA, tAE, tB, tC);
    wr8<1>(b0, a0, xa); wr8<1>(b1, a0, xb); }
  __syncthreads();

  f2 xr[10], xi[10];          // .x = elem A, .y = elem B
  f2 S, zz0, zz1, zz2;
  // ---- FFT pass 3 (span 1) fused with qubit 0,1,2 expectations ----
  { const int a0 = swz(t << 3);
    rd8<0>(b0, a0, xa); rd8<0>(b1, a0, xb);
    #pragma unroll
    for (int m = 0; m < 8; m += 2){
      f2 u = xa[m] + xa[m+1], v = xa[m] - xa[m+1];
      xa[m] = u; xa[m+1] = v;
      u = xb[m] + xb[m+1]; v = xb[m] - xb[m+1];
      xb[m] = u; xb[m+1] = v;
    }
    wr8<0>(b0, a0, xa); wr8<0>(b1, a0, xb);
    float nA[8], nB[8];
    #pragma unroll
    for (int m = 0; m < 8; ++m){
      f2 q = xa[m]*xa[m]; nA[m] = q.x + q.y;
      q = xb[m]*xb[m];    nB[m] = q.x + q.y;
    }
    S   = f2{nA[0]+nA[1]+nA[2]+nA[3]+nA[4]+nA[5]+nA[6]+nA[7],
             nB[0]+nB[1]+nB[2]+nB[3]+nB[4]+nB[5]+nB[6]+nB[7]};
    zz0 = f2{(nA[0]+nA[2]+nA[4]+nA[6]) - (nA[1]+nA[3]+nA[5]+nA[7]),
             (nB[0]+nB[2]+nB[4]+nB[6]) - (nB[1]+nB[3]+nB[5]+nB[7])};
    zz1 = f2{(nA[0]+nA[1]+nA[4]+nA[5]) - (nA[2]+nA[3]+nA[6]+nA[7]),
             (nB[0]+nB[1]+nB[4]+nB[5]) - (nB[2]+nB[3]+nB[6]+nB[7])};
    zz2 = f2{(nA[0]+nA[1]+nA[2]+nA[3]) - (nA[4]+nA[5]+nA[6]+nA[7]),
             (nB[0]+nB[1]+nB[2]+nB[3]) - (nB[4]+nB[5]+nB[6]+nB[7])};
    float rA,iA,rB,iB;
    pairsum<1>(xa,rA,iA); pairsum<1>(xb,rB,iB); xr[0]=f2{rA,rB}; xi[0]=f2{iA,iB};
    pairsum<2>(xa,rA,iA); pairsum<2>(xb,rB,iB); xr[1]=f2{rA,rB}; xi[1]=f2{iA,iB};
    pairsum<4>(xa,rA,iA); pairsum<4>(xb,rB,iB); xr[2]=f2{rA,rB}; xi[2]=f2{iA,iB};
  }
  __syncthreads();

  // ---- expectation read passes (read-only) ----
  { const int a0 = swz(baseS<3>(t));
    rd8<3>(b0, a0, xa); rd8<3>(b1, a0, xb);
    float rA,iA,rB,iB;
    pairsum<1>(xa,rA,iA); pairsum<1>(xb,rB,iB); xr[3]=f2{rA,rB}; xi[3]=f2{iA,iB};
    pairsum<2>(xa,rA,iA); pairsum<2>(xb,rB,iB); xr[4]=f2{rA,rB}; xi[4]=f2{iA,iB};
    pairsum<4>(xa,rA,iA); pairsum<4>(xb,rB,iB); xr[5]=f2{rA,rB}; xi[5]=f2{iA,iB}; }
  { const int a0 = swz(baseS<6>(t));
    rd8<6>(b0, a0, xa); rd8<6>(b1, a0, xb);
    float rA,iA,rB,iB;
    pairsum<1>(xa,rA,iA); pairsum<1>(xb,rB,iB); xr[6]=f2{rA,rB}; xi[6]=f2{iA,iB};
    pairsum<2>(xa,rA,iA); pairsum<2>(xb,rB,iB); xr[7]=f2{rA,rB}; xi[7]=f2{iA,iB};
    pairsum<4>(xa,rA,iA); pairsum<4>(xb,rB,iB); xr[8]=f2{rA,rB}; xi[8]=f2{iA,iB}; }
  { f2 rpA = {0.f,0.f}, ipA = {0.f,0.f}, rpB = {0.f,0.f}, ipB = {0.f,0.f};
    #pragma unroll
    for (int u = 0; u < 4; ++u){
      const int a1 = st ^ swz(u << 7), a2 = a1 ^ swz(512);
      const f2 aA = b0[a1], cA = b0[a2];
      const f2 aB = b1[a1], cB = b1[a2];
      rpA = aA*cA + rpA; ipA = pk_cross(aA, cA, ipA);
      rpB = aB*cB + rpB; ipB = pk_cross(aB, cB, ipB);
    }
    xr[9] = f2{rpA.x + rpA.y, rpB.x + rpB.y};
    xi[9] = f2{ipA.x + ipA.y, ipB.x + ipB.y}; }
  __syncthreads();   // all state reads done; buf becomes reduction rows

  // ---- packed Walsh-Hadamard on S -> Z_3..Z_9 ----
  { f2 s = S, d0,d1,d2,d3,d4,d5, wv;
    wv = shfl_xor_f2(s, 1);  d0 = (lane & 1)  ? (wv - s) : (s - wv); s += wv;
    wv = shfl_xor_f2(s, 2);  d1 = (lane & 2)  ? (wv - s) : (s - wv); s += wv;
    wv = shfl_xor_f2(s, 4);  d2 = (lane & 4)  ? (wv - s) : (s - wv); s += wv;
    wv = shfl_xor_f2(s, 8);  d3 = (lane & 8)  ? (wv - s) : (s - wv); s += wv;
    wv = shfl_xor_f2(s, 16); d4 = (lane & 16) ? (wv - s) : (s - wv); s += wv;
    wv = shfl_xor_f2(s, 32); d5 = (lane & 32) ? (wv - s) : (s - wv); s += wv;
    d0 += shfl_xor_f2(d0, 2); d0 += shfl_xor_f2(d0, 4); d0 += shfl_xor_f2(d0, 8); d0 += shfl_xor_f2(d0, 16); d0 += shfl_xor_f2(d0, 32);
    d1 += shfl_xor_f2(d1, 4); d1 += shfl_xor_f2(d1, 8); d1 += shfl_xor_f2(d1, 16); d1 += shfl_xor_f2(d1, 32);
    d2 += shfl_xor_f2(d2, 8); d2 += shfl_xor_f2(d2, 16); d2 += shfl_xor_f2(d2, 32);
    d3 += shfl_xor_f2(d3, 16); d3 += shfl_xor_f2(d3, 32);
    d4 += shfl_xor_f2(d4, 32);
    if (lane == 0){
      wzS[wave][0] = s;
      wzS[wave][1] = d0; wzS[wave][2] = d1; wzS[wave][3] = d2;
      wzS[wave][4] = d3; wzS[wave][5] = d4; wzS[wave][6] = d5;
    }
  }

  // ---- stage 1: packed pre-reduce (masks 16,32), write per-elem rows ----
  #pragma unroll
  for (int q = 0; q < 10; ++q){
    xr[q] += shfl_xor_f2(xr[q], 16); xr[q] += shfl_xor_f2(xr[q], 32);
    xi[q] += shfl_xor_f2(xi[q], 16); xi[q] += shfl_xor_f2(xi[q], 32);
  }
  zz0 += shfl_xor_f2(zz0, 16); zz0 += shfl_xor_f2(zz0, 32);
  zz1 += shfl_xor_f2(zz1, 16); zz1 += shfl_xor_f2(zz1, 32);
  zz2 += shfl_xor_f2(zz2, 16); zz2 += shfl_xor_f2(zz2, 32);
  if (lane < 16){
    const int col = wave*16 + lane;
    #pragma unroll
    for (int q = 0; q < 10; ++q){
      b0[q*33 + col] = f2{xr[q].x, xi[q].x};
      b1[q*33 + col] = f2{xr[q].y, xi[q].y};
    }
    b0[10*33 + col] = f2{zz0.x, zz1.x};  b1[10*33 + col] = f2{zz0.y, zz1.y};
    b0[11*33 + col] = f2{zz2.x, 0.f};    b1[11*33 + col] = f2{zz2.y, 0.f};
  }
  __syncthreads();

  // ---- stage 2 ----
  const float xs = 2.0f/1024.0f, zs = 1.0f/1024.0f;
  float* obA = out + (size_t)(2*b) * 30;
  float* obB = obA + 30;
  if (t < 96){
    const int r = t >> 3, c = t & 7;
    f2 vA = b0[r*33+c] + b0[r*33+c+8] + b0[r*33+c+16] + b0[r*33+c+24];
    f2 vB = b1[r*33+c] + b1[r*33+c+8] + b1[r*33+c+16] + b1[r*33+c+24];
    vA += shfl_xor_f2(vA, 1); vA += shfl_xor_f2(vA, 2); vA += shfl_xor_f2(vA, 4);
    vB += shfl_xor_f2(vB, 1); vB += shfl_xor_f2(vB, 2); vB += shfl_xor_f2(vB, 4);
    if (c == 0){
      if (r < 10){
        obA[r] = vA.x*xs; obA[10+r] = vA.y*xs;
        obB[r] = vB.x*xs; obB[10+r] = vB.y*xs;
      } else if (r == 10){
        obA[20] = vA.x*zs; obA[21] = vA.y*zs;
        obB[20] = vB.x*zs; obB[21] = vB.y*zs;
      } else {
        obA[22] = vA.x*zs; obB[22] = vB.x*zs;
      }
    }
  }
  if (t >= 120 && t < 127){
    const int k = t - 120;
    if (k < 6){
      const f2 v = wzS[0][1+k] + wzS[1][1+k];
      obA[23+k] = v.x*zs; obB[23+k] = v.y*zs;
    } else {
      const f2 v = wzS[0][0] - wzS[1][0];
      obA[29] = v.x*zs; obB[29] = v.y*zs;
    }
  }
}

extern "C" void kernel_launch(void* const* d_in, const int* in_sizes, int n_in,
                              void* d_out, int out_size, void* d_ws, size_t ws_size,
                              hipStream_t stream) {
  const float* x = (const float*)d_in[0];
  const float* w = (const float*)d_in[1];
  float* out = (float*)d_out;
  float* gt  = (float*)d_ws;           // 100 floats of gate tables
  const int B = in_sizes[0] / NFEAT;   // 8192
  gate_prep<<<1, 16, 0, stream>>>(w, gt);
  qqk_kernel<<<B/2, NT, 0, stream>>>(x, gt, out);
}

// Round 7
// 47.529 us; speedup vs baseline: 1.9877x; 1.9877x over previous
//
#include <hip/hip_runtime.h>
#include <math.h>

#define NFEAT 768
#define NT    256   // 4 independent waves per block; 1 wave = 1 batch element; ZERO __syncthreads

typedef float f2 __attribute__((ext_vector_type(2)));

// GF2-linear LDS swizzle (bijective; bank-spread verified for layouts A/B/C + gather)
__device__ __forceinline__ int swz(int j){ return j ^ (j >> 4) ^ ((j >> 2) & 0xC); }

// Composite of the CNOT ring CNOT(0,1),...,CNOT(9,0): s_after[j] = s_before[perm(j)]. GF2-linear.
__device__ __forceinline__ int cnot_perm(int j){
  int i = j;
  i ^= ((i >> 0) & 1) << 9;
  i ^= ((i >> 1) & 1) << 0;
  i ^= ((i >> 2) & 1) << 1;
  i ^= ((i >> 3) & 1) << 2;
  i ^= ((i >> 4) & 1) << 3;
  i ^= ((i >> 5) & 1) << 4;
  i ^= ((i >> 6) & 1) << 5;
  i ^= ((i >> 7) & 1) << 6;
  i ^= ((i >> 8) & 1) << 7;
  i ^= ((i >> 9) & 1) << 8;
  return i;
}

// ---- DPP cross-lane (VALU pipe, not DS): quad_perm xor1=0xB1, xor2=0x4E ----
template<int CTRL>
__device__ __forceinline__ float dpp_mov(float x){
  return __builtin_bit_cast(float,
    __builtin_amdgcn_update_dpp(0, __builtin_bit_cast(int, x), CTRL, 0xF, 0xF, true));
}
template<int CTRL>
__device__ __forceinline__ float dpp_add(float x){ return x + dpp_mov<CTRL>(x); }

// ---- packed-f32 complex primitives (VOP3P, verified R5) ----
__device__ __forceinline__ f2 pk_cmul(f2 s, f2 v){
  f2 d;
  asm("v_pk_mul_f32 %0, %1, %2 op_sel:[0,0] op_sel_hi:[0,1]\n\t"
      "v_pk_fma_f32 %0, %1, %2, %0 op_sel:[1,1,0] op_sel_hi:[1,0,1] neg_lo:[0,1,0]"
      : "=&v"(d) : "v"(s), "v"(v));
  return d;
}
__device__ __forceinline__ f2 pk_cfma(f2 s, f2 v, f2 acc){
  f2 d;
  asm("v_pk_fma_f32 %0, %2, %3, %1 op_sel:[0,0,0] op_sel_hi:[0,1,1]\n\t"
      "v_pk_fma_f32 %0, %2, %3, %0 op_sel:[1,1,0] op_sel_hi:[1,0,1] neg_lo:[0,1,0]"
      : "=&v"(d) : "v"(acc), "v"(s), "v"(v));
  return d;
}
// d = acc + (a.r*b.i, -a.i*b.r)   (Im<conj(a) b> accumulation)
__device__ __forceinline__ f2 pk_cross(f2 a, f2 b, f2 acc){
  f2 d;
  asm("v_pk_fma_f32 %0, %2, %3, %1 op_sel:[0,1,0] op_sel_hi:[1,0,1] neg_hi:[1,0,0]"
      : "=&v"(d) : "v"(acc), "v"(a), "v"(b));
  return d;
}
__device__ __forceinline__ void pk_ry(f2 cs, f2& a, f2& b){
  f2 t1, t2, na, nb;
  asm("v_pk_mul_f32 %0, %2, %3 op_sel:[1,0] op_sel_hi:[1,1] neg_lo:[1,0] neg_hi:[1,0]\n\t"
      "v_pk_mul_f32 %1, %2, %4 op_sel:[1,0] op_sel_hi:[1,1]"
      : "=&v"(t1), "=&v"(t2) : "v"(cs), "v"(b), "v"(a));
  asm("v_pk_fma_f32 %0, %2, %3, %4 op_sel:[0,0,0] op_sel_hi:[0,1,1]\n\t"
      "v_pk_fma_f32 %1, %2, %5, %6 op_sel:[0,0,0] op_sel_hi:[0,1,1]"
      : "=&v"(na), "=&v"(nb) : "v"(cs), "v"(a), "v"(t1), "v"(b), "v"(t2));
  a = na; b = nb;
}
__device__ __forceinline__ void gateU(const f2* g, f2& a, f2& b){
  const f2 na = pk_cfma(g[1], b, pk_cmul(g[0], a));
  const f2 nb = pk_cfma(g[3], b, pk_cmul(g[2], a));
  a = na; b = nb;
}
// DIF butterfly: a'=a+b ; b'=(a-b)*tw   (+ tw=1 / tw=i fast forms)
__device__ __forceinline__ void bfly(f2& a, f2& b, f2 tw){
  const f2 u = a + b, v = a - b;
  a = u; b = pk_cmul(tw, v);
}
__device__ __forceinline__ void bfly1(f2& a, f2& b){
  const f2 u = a + b, v = a - b; a = u; b = v;
}
__device__ __forceinline__ void bflyI(f2& a, f2& b){
  const f2 u = a + b, v = a - b; a = u; b = f2{-v.y, v.x};
}

template<int MASK>
__device__ __forceinline__ void gate_on(f2* xv, const f2* g){
  #pragma unroll
  for (int m = 0; m < 16; ++m) if (!(m & MASK)) gateU(g, xv[m], xv[m|MASK]);
}
template<int MASK>
__device__ __forceinline__ void ry_on(f2* xv, const f2 cs){
  #pragma unroll
  for (int m = 0; m < 16; ++m) if (!(m & MASK)) pk_ry(cs, xv[m], xv[m|MASK]);
}

template<int SH>
__device__ __forceinline__ void rd16(const f2* bb, int a0, f2* xv){
  #pragma unroll
  for (int m = 0; m < 16; ++m) xv[m] = bb[a0 ^ swz(m << SH)];
}
template<int SH>
__device__ __forceinline__ void wr16(f2* bb, int a0, const f2* xv){
  #pragma unroll
  for (int m = 0; m < 16; ++m) bb[a0 ^ swz(m << SH)] = xv[m];
}

// 4 DIF radix-2 stages on 16 regs; twiddles: BT*T64^m, BT^2*T128^k, BT^4*{1,i}, BT^8.
// Matches stage twiddle law e=(i mod h)*(1024/2h) for layouts A (BT=T(lane)) and B (BT=T(16*(lane&3))).
__device__ __forceinline__ void fft16(f2* xv, const f2 BT){
  const f2 T64c  = { 0.9238795325112867f, 0.3826834323650898f };   // T(64)
  const f2 T128c = { 0.7071067811865476f, 0.7071067811865476f };   // T(128)
  const f2 tB = pk_cmul(BT, BT);
  const f2 tC = pk_cmul(tB, tB);
  const f2 tD = pk_cmul(tC, tC);
  { f2 tw = BT;                               // stage span: pairs m, m+8
    bfly(xv[0], xv[8], tw);
    #pragma unroll
    for (int m = 1; m < 8; ++m){ tw = pk_cmul(tw, T64c); bfly(xv[m], xv[m+8], tw); } }
  { f2 tw = tB;                               // pairs m, m+4
    bfly(xv[0], xv[4], tw); bfly(xv[8], xv[12], tw);
    #pragma unroll
    for (int k = 1; k < 4; ++k){ tw = pk_cmul(tw, T128c); bfly(xv[k], xv[k+4], tw); bfly(xv[8+k], xv[12+k], tw); } }
  { const f2 itC = {-tC.y, tC.x};             // pairs m, m+2
    #pragma unroll
    for (int m = 0; m < 16; ++m) if (!(m & 2)) bfly(xv[m], xv[m|2], (m & 1) ? itC : tC); }
  #pragma unroll
  for (int m = 0; m < 16; m += 2) bfly(xv[m], xv[m+1], tD);
}

template<int MASK>
__device__ __forceinline__ f2 pairsum16(const f2* z){
  f2 rp = {0.f, 0.f}, ip = {0.f, 0.f};
  #pragma unroll
  for (int m = 0; m < 16; ++m) if (!(m & MASK)){
    rp = z[m]*z[m|MASK] + rp;
    ip = pk_cross(z[m], z[m|MASK], ip);
  }
  return f2{ rp.x + rp.y, ip.x + ip.y };   // (Re, Im) of sum conj(a)*b
}

__global__ void gate_prep(const float* __restrict__ w, float* __restrict__ gt){
  const int t = threadIdx.x;
  if (t >= 10) return;
  const float ha = 0.5f*w[t*4+0], hb = 0.5f*w[t*4+1];
  const float hg = 0.5f*w[t*4+2], hd = 0.5f*w[t*4+3];
  const float ca = cosf(ha), sa = sinf(ha);
  const float cb = cosf(hb), sb = sinf(hb);
  const float cg = cosf(hg), sg = sinf(hg);
  const float m00r = cb*ca, m00i =  sb*sa;
  const float m01r = -sb*ca, m01i = -cb*sa;
  const float m10r =  sb*ca, m10i = -cb*sa;
  const float m11r = cb*ca,  m11i = -sb*sa;
  gt[8*t+0] = cg*m00r + sg*m00i;  gt[8*t+1] = cg*m00i - sg*m00r;
  gt[8*t+2] = cg*m01r + sg*m01i;  gt[8*t+3] = cg*m01i - sg*m01r;
  gt[8*t+4] = cg*m10r - sg*m10i;  gt[8*t+5] = cg*m10i + sg*m10r;
  gt[8*t+6] = cg*m11r - sg*m11i;  gt[8*t+7] = cg*m11i + sg*m11r;
  gt[80+2*t] = cosf(hd); gt[81+2*t] = sinf(hd);
}

__global__ void __launch_bounds__(NT)   // NO waves-per-EU hint (R3/R6 spill lesson)
qqk_kernel(const float* __restrict__ x, const float* __restrict__ gt,
           float* __restrict__ out)
{
  __shared__ f2 smem[4*1024];            // one 1024-f2 state buffer per wave
  const int t = threadIdx.x, wave = t >> 6, lane = t & 63;
  f2* bb = smem + (wave << 10);
  const f2* g2  = (const f2*)gt;         // 10 gates x (u00,u01,u10,u11)
  const f2* gry = (const f2*)(gt + 80);  // 10 x (cos,sin)
  const size_t e = (size_t)blockIdx.x * 4 + wave;
  const float* xg = x + e * NFEAT;

  // layout bases: A: i = m<<6|lane ; B: i = (lane>>2)<<6|m<<2|(lane&3) ; C: i = lane<<4|m
  const int aA = swz(lane);
  const int aB = swz(((lane >> 2) << 6) | (lane & 3));
  const int aC = swz(lane << 4);

  f2 xv[16];
  // ---- P0: global load + norm + gates q0-3 (bits 9..6 = m masks 8,4,2,1), write A ----
  float ss = 0.f;
  #pragma unroll
  for (int m = 0; m < 12; ++m){ const float v = xg[(m << 6) + lane]; xv[m] = f2{v, 0.f}; ss += v*v; }
  #pragma unroll
  for (int m = 12; m < 16; ++m) xv[m] = f2{0.f, 0.f};
  ss = dpp_add<0xB1>(ss); ss = dpp_add<0x4E>(ss);
  ss += __shfl_xor(ss, 4); ss += __shfl_xor(ss, 8); ss += __shfl_xor(ss, 16); ss += __shfl_xor(ss, 32);
  const float invn = 1.0f / fmaxf(sqrtf(ss), 1e-8f);
  #pragma unroll
  for (int m = 0; m < 12; ++m) xv[m].x *= invn;
  gate_on<8>(xv, g2+0); gate_on<4>(xv, g2+4); gate_on<2>(xv, g2+8); gate_on<1>(xv, g2+12);
  wr16<6>(bb, aA, xv);
  // ---- P1: gates q4-7 (bits 5..2) ----
  rd16<2>(bb, aB, xv);
  gate_on<8>(xv, g2+16); gate_on<4>(xv, g2+20); gate_on<2>(xv, g2+24); gate_on<1>(xv, g2+28);
  wr16<2>(bb, aB, xv);
  // ---- P2: gates q8,q9 (bits 1,0) ----
  rd16<0>(bb, aC, xv);
  gate_on<2>(xv, g2+32); gate_on<1>(xv, g2+36);
  wr16<0>(bb, aC, xv);
  // ---- P3: CNOT-ring gather (all reads precede writes in wave program order) + RY q0-3 ----
  { const int ag = swz(cnot_perm(lane));
    #pragma unroll
    for (int m = 0; m < 16; ++m) xv[m] = bb[ag ^ swz(cnot_perm(m << 6))];
  }
  ry_on<8>(xv, gry[0]); ry_on<4>(xv, gry[1]); ry_on<2>(xv, gry[2]); ry_on<1>(xv, gry[3]);
  wr16<6>(bb, aA, xv);
  // ---- P4: RY q4-7 ----
  rd16<2>(bb, aB, xv);
  ry_on<8>(xv, gry[4]); ry_on<4>(xv, gry[5]); ry_on<2>(xv, gry[6]); ry_on<1>(xv, gry[7]);
  wr16<2>(bb, aB, xv);
  // ---- P5: RY q8,q9 ----
  rd16<0>(bb, aC, xv);
  ry_on<2>(xv, gry[8]); ry_on<1>(xv, gry[9]);
  wr16<0>(bb, aC, xv);
  // ---- P6: FFT stages span 512,256,128,64 (layout A, BT = T(lane)) ----
  rd16<6>(bb, aA, xv);
  { float sa, ca; __sincosf((float)lane * 6.135923151542565e-3f, &sa, &ca);
    fft16(xv, f2{ca, sa}); }
  wr16<6>(bb, aA, xv);
  // ---- P7: FFT stages span 32,16,8,4 (layout B, BT = T(16*(lane&3))) ----
  rd16<2>(bb, aB, xv);
  { float sa, ca; __sincosf((float)(lane & 3) * 9.817477042468104e-2f, &sa, &ca);
    fft16(xv, f2{ca, sa}); }
  wr16<2>(bb, aB, xv);
  // ---- P8: FFT stages span 2,1 + expectations q0-3 + probabilities (layout C) ----
  rd16<0>(bb, aC, xv);
  #pragma unroll
  for (int m = 0; m < 16; ++m) if (!(m & 2)){ if (m & 1) bflyI(xv[m], xv[m|2]); else bfly1(xv[m], xv[m|2]); }
  #pragma unroll
  for (int m = 0; m < 16; m += 2) bfly1(xv[m], xv[m+1]);
  wr16<0>(bb, aC, xv);
  f2 xrxi[10];
  xrxi[0] = pairsum16<1>(xv); xrxi[1] = pairsum16<2>(xv);
  xrxi[2] = pairsum16<4>(xv); xrxi[3] = pairsum16<8>(xv);
  float S = 0.f, z0 = 0.f, z1 = 0.f, z2 = 0.f, z3 = 0.f;
  #pragma unroll
  for (int m = 0; m < 16; ++m){
    const f2 q = xv[m]*xv[m]; const float n = q.x + q.y;
    S += n;
    z0 += (m & 1) ? -n : n;  z1 += (m & 2) ? -n : n;
    z2 += (m & 4) ? -n : n;  z3 += (m & 8) ? -n : n;
  }
  // ---- P9 (read-only, layout A): qubits 6..9 ----
  rd16<6>(bb, aA, xv);
  xrxi[6] = pairsum16<1>(xv); xrxi[7] = pairsum16<2>(xv);
  xrxi[8] = pairsum16<4>(xv); xrxi[9] = pairsum16<8>(xv);
  // ---- P10 (read-only, layout B): qubits 4,5 ----
  rd16<2>(bb, aB, xv);
  xrxi[4] = pairsum16<4>(xv); xrxi[5] = pairsum16<8>(xv);

  // ---- Walsh-Hadamard over lane bits on S -> Z4..Z9 (all lanes end with totals) ----
  float d0, d1, d2, d3, d4, d5;
  { float s = S, wv;
    wv = dpp_mov<0xB1>(s); d0 = (lane & 1)  ? (wv - s) : (s - wv); s += wv;
    wv = dpp_mov<0x4E>(s); d1 = (lane & 2)  ? (wv - s) : (s - wv); s += wv;
    wv = __shfl_xor(s, 4);  d2 = (lane & 4)  ? (wv - s) : (s - wv); s += wv;
    wv = __shfl_xor(s, 8);  d3 = (lane & 8)  ? (wv - s) : (s - wv); s += wv;
    wv = __shfl_xor(s, 16); d4 = (lane & 16) ? (wv - s) : (s - wv); s += wv;
    wv = __shfl_xor(s, 32); d5 = (lane & 32) ? (wv - s) : (s - wv); s += wv;
    d0 = dpp_add<0x4E>(d0); d0 += __shfl_xor(d0, 4); d0 += __shfl_xor(d0, 8); d0 += __shfl_xor(d0, 16); d0 += __shfl_xor(d0, 32);
    d1 += __shfl_xor(d1, 4); d1 += __shfl_xor(d1, 8); d1 += __shfl_xor(d1, 16); d1 += __shfl_xor(d1, 32);
    d2 += __shfl_xor(d2, 8); d2 += __shfl_xor(d2, 16); d2 += __shfl_xor(d2, 32);
    d3 += __shfl_xor(d3, 16); d3 += __shfl_xor(d3, 32);
    d4 += __shfl_xor(d4, 32);
  }

  // ---- 24-scalar reduce: quad pre-sum via DPP (VALU), then LDS row transpose (state dead) ----
  #pragma unroll
  for (int q = 0; q < 10; ++q){
    xrxi[q].x = dpp_add<0x4E>(dpp_add<0xB1>(xrxi[q].x));
    xrxi[q].y = dpp_add<0x4E>(dpp_add<0xB1>(xrxi[q].y));
  }
  z0 = dpp_add<0x4E>(dpp_add<0xB1>(z0));
  z1 = dpp_add<0x4E>(dpp_add<0xB1>(z1));
  z2 = dpp_add<0x4E>(dpp_add<0xB1>(z2));
  z3 = dpp_add<0x4E>(dpp_add<0xB1>(z3));
  float* rb = (float*)bb;                    // rows: 24 x 16 floats (reuses dead state LDS)
  const int g = lane >> 2;
  if ((lane & 3) == 0){
    #pragma unroll
    for (int q = 0; q < 10; ++q){ rb[q*16 + g] = xrxi[q].x; rb[(10+q)*16 + g] = xrxi[q].y; }
    rb[20*16 + g] = z0; rb[21*16 + g] = z1; rb[22*16 + g] = z2; rb[23*16 + g] = z3;
  }
  // same-wave DS ordering: row reads below see the writes above
  float* ob = out + e * 30;
  if (lane < 24){
    float acc = 0.f;
    #pragma unroll
    for (int gg = 0; gg < 16; ++gg) acc += rb[lane*16 + gg];
    ob[lane] = acc * ((lane < 20) ? (2.0f/1024.0f) : (1.0f/1024.0f));
  }
  if (lane == 0){
    const float zs = 1.0f/1024.0f;
    ob[24] = d0*zs; ob[25] = d1*zs; ob[26] = d2*zs;
    ob[27] = d3*zs; ob[28] = d4*zs; ob[29] = d5*zs;
  }
}

extern "C" void kernel_launch(void* const* d_in, const int* in_sizes, int n_in,
                              void* d_out, int out_size, void* d_ws, size_t ws_size,
                              hipStream_t stream) {
  const float* x = (const float*)d_in[0];
  const float* w = (const float*)d_in[1];
  float* out = (float*)d_out;
  float* gt  = (float*)d_ws;           // 100 floats of gate tables
  const int B = in_sizes[0] / NFEAT;   // 8192
  gate_prep<<<1, 16, 0, stream>>>(w, gt);
  qqk_kernel<<<B/4, NT, 0, stream>>>(x, gt, out);
}

// Round 10
// 45.606 us; speedup vs baseline: 2.0715x; 1.0422x over previous
//
#include <hip/hip_runtime.h>
#include <math.h>

#define NFEAT 768
#define NT    256   // 4 waves/block, 1 wave = 1 element, ZERO barriers (R7-proven shape)

typedef float f2 __attribute__((ext_vector_type(2)));
#define MEMFENCE() asm volatile("" ::: "memory")

// bit0-preserving GF2-linear swizzle: addr bits 3..1 ^= index bits 6..4.
// Keeps slot-pairs (indices differing in bit0) LDS-adjacent -> b128 I/O.
__device__ __forceinline__ int swz2(int j){ return j ^ ((j >> 3) & 0xE); }

// Composite of the CNOT ring CNOT(0,1),...,CNOT(9,0): s_after[j] = s_before[perm(j)]. GF2-linear.
__device__ __forceinline__ int cnot_perm(int j){
  int i = j;
  i ^= ((i >> 0) & 1) << 9;
  i ^= ((i >> 1) & 1) << 0;
  i ^= ((i >> 2) & 1) << 1;
  i ^= ((i >> 3) & 1) << 2;
  i ^= ((i >> 4) & 1) << 3;
  i ^= ((i >> 5) & 1) << 4;
  i ^= ((i >> 6) & 1) << 5;
  i ^= ((i >> 7) & 1) << 6;
  i ^= ((i >> 8) & 1) << 7;
  i ^= ((i >> 9) & 1) << 8;
  return i;
}

// ---- DPP cross-lane (VALU pipe): quad_perm xor1=0xB1, xor2=0x4E ----
template<int CTRL>
__device__ __forceinline__ float dpp_mov(float x){
  return __builtin_bit_cast(float,
    __builtin_amdgcn_update_dpp(0, __builtin_bit_cast(int, x), CTRL, 0xF, 0xF, true));
}
template<int CTRL>
__device__ __forceinline__ float dpp_add(float x){ return x + dpp_mov<CTRL>(x); }

// ---- packed-f32 complex primitives (VOP3P, verified R5/R7) ----
__device__ __forceinline__ f2 pk_cmul(f2 s, f2 v){
  f2 d;
  asm("v_pk_mul_f32 %0, %1, %2 op_sel:[0,0] op_sel_hi:[0,1]\n\t"
      "v_pk_fma_f32 %0, %1, %2, %0 op_sel:[1,1,0] op_sel_hi:[1,0,1] neg_lo:[0,1,0]"
      : "=&v"(d) : "v"(s), "v"(v));
  return d;
}
__device__ __forceinline__ f2 pk_cfma(f2 s, f2 v, f2 acc){
  f2 d;
  asm("v_pk_fma_f32 %0, %2, %3, %1 op_sel:[0,0,0] op_sel_hi:[0,1,1]\n\t"
      "v_pk_fma_f32 %0, %2, %3, %0 op_sel:[1,1,0] op_sel_hi:[1,0,1] neg_lo:[0,1,0]"
      : "=&v"(d) : "v"(acc), "v"(s), "v"(v));
  return d;
}
// d = acc + (a.r*b.i, -a.i*b.r)
__device__ __forceinline__ f2 pk_cross(f2 a, f2 b, f2 acc){
  f2 d;
  asm("v_pk_fma_f32 %0, %2, %3, %1 op_sel:[0,1,0] op_sel_hi:[1,0,1] neg_hi:[1,0,0]"
      : "=&v"(d) : "v"(acc), "v"(a), "v"(b));
  return d;
}
__device__ __forceinline__ void pk_ry(f2 cs, f2& a, f2& b){
  f2 t1, t2, na, nb;
  asm("v_pk_mul_f32 %0, %2, %3 op_sel:[1,0] op_sel_hi:[1,1] neg_lo:[1,0] neg_hi:[1,0]\n\t"
      "v_pk_mul_f32 %1, %2, %4 op_sel:[1,0] op_sel_hi:[1,1]"
      : "=&v"(t1), "=&v"(t2) : "v"(cs), "v"(b), "v"(a));
  asm("v_pk_fma_f32 %0, %2, %3, %4 op_sel:[0,0,0] op_sel_hi:[0,1,1]\n\t"
      "v_pk_fma_f32 %1, %2, %5, %6 op_sel:[0,0,0] op_sel_hi:[0,1,1]"
      : "=&v"(na), "=&v"(nb) : "v"(cs), "v"(a), "v"(t1), "v"(b), "v"(t2));
  a = na; b = nb;
}
__device__ __forceinline__ void gateU(const f2* g, f2& a, f2& b){
  const f2 na = pk_cfma(g[1], b, pk_cmul(g[0], a));
  const f2 nb = pk_cfma(g[3], b, pk_cmul(g[2], a));
  a = na; b = nb;
}
__device__ __forceinline__ f2 rot90(f2 v){ return f2{-v.y, v.x}; }
__device__ __forceinline__ void bfly(f2& a, f2& b, f2 tw){
  const f2 u = a + b, v = a - b;
  a = u; b = pk_cmul(tw, v);
}
__device__ __forceinline__ void bfly1(f2& a, f2& b){
  const f2 u = a + b, v = a - b; a = u; b = v;
}
__device__ __forceinline__ void bflyI(f2& a, f2& b){
  const f2 u = a + b, v = a - b; a = u; b = f2{-v.y, v.x};
}

template<int MASK>
__device__ __forceinline__ void gate_on(f2* xv, const f2* g){
  #pragma unroll
  for (int m = 0; m < 16; ++m) if (!(m & MASK)) gateU(g, xv[m], xv[m|MASK]);
}
template<int MASK>
__device__ __forceinline__ void ry_on(f2* xv, const f2 cs){
  #pragma unroll
  for (int m = 0; m < 16; ++m) if (!(m & MASK)) pk_ry(cs, xv[m], xv[m|MASK]);
}
template<int MASK>
__device__ __forceinline__ f2 pairsum16(const f2* z){
  f2 rp = {0.f, 0.f}, ip = {0.f, 0.f};
  #pragma unroll
  for (int m = 0; m < 16; ++m) if (!(m & MASK)){
    rp = z[m]*z[m|MASK] + rp;
    ip = pk_cross(z[m], z[m|MASK], ip);
  }
  return f2{ rp.x + rp.y, ip.x + ip.y };
}

// ---- b128-paired LDS I/O: slots (2k,2k+1) adjacent, 16B aligned ----
// A': idx = (m>>1)<<7 | lane<<1 | (m&1)  (in-reg index bits {9,8,7,0})
// B': idx = (lane>>3)<<7 | (m>>1)<<4 | (lane&7)<<1 | (m&1)   ({6,5,4,0})
// C': idx = lane<<4 | m                                      ({3,2,1,0})
__device__ __forceinline__ void rdA(const f2* bb, int a0, f2* xv){
  #pragma unroll
  for (int k = 0; k < 8; ++k){
    const float4 v = *(const float4*)(bb + (a0 ^ (k << 7)));
    xv[2*k] = f2{v.x, v.y}; xv[2*k+1] = f2{v.z, v.w};
  }
}
__device__ __forceinline__ void wrA(f2* bb, int a0, const f2* xv){
  #pragma unroll
  for (int k = 0; k < 8; ++k)
    *(float4*)(bb + (a0 ^ (k << 7))) = make_float4(xv[2*k].x, xv[2*k].y, xv[2*k+1].x, xv[2*k+1].y);
}
__device__ __forceinline__ void rdB(const f2* bb, int a0, f2* xv){
  #pragma unroll
  for (int k = 0; k < 8; ++k){
    const float4 v = *(const float4*)(bb + (a0 ^ ((k << 4) | (k << 1))));
    xv[2*k] = f2{v.x, v.y}; xv[2*k+1] = f2{v.z, v.w};
  }
}
__device__ __forceinline__ void wrB(f2* bb, int a0, const f2* xv){
  #pragma unroll
  for (int k = 0; k < 8; ++k)
    *(float4*)(bb + (a0 ^ ((k << 4) | (k << 1)))) = make_float4(xv[2*k].x, xv[2*k].y, xv[2*k+1].x, xv[2*k+1].y);
}
__device__ __forceinline__ void rdC(const f2* bb, int a0, f2* xv){
  #pragma unroll
  for (int k = 0; k < 8; ++k){
    const float4 v = *(const float4*)(bb + (a0 ^ (k << 1)));
    xv[2*k] = f2{v.x, v.y}; xv[2*k+1] = f2{v.z, v.w};
  }
}
__device__ __forceinline__ void wrC(f2* bb, int a0, const f2* xv){
  #pragma unroll
  for (int k = 0; k < 8; ++k)
    *(float4*)(bb + (a0 ^ (k << 1))) = make_float4(xv[2*k].x, xv[2*k].y, xv[2*k+1].x, xv[2*k+1].y);
}

__global__ void gate_prep(const float* __restrict__ w, float* __restrict__ gt){
  const int t = threadIdx.x;
  if (t >= 10) return;
  const float ha = 0.5f*w[t*4+0], hb = 0.5f*w[t*4+1];
  const float hg = 0.5f*w[t*4+2], hd = 0.5f*w[t*4+3];
  const float ca = cosf(ha), sa = sinf(ha);
  const float cb = cosf(hb), sb = sinf(hb);
  const float cg = cosf(hg), sg = sinf(hg);
  const float m00r = cb*ca, m00i =  sb*sa;
  const float m01r = -sb*ca, m01i = -cb*sa;
  const float m10r =  sb*ca, m10i = -cb*sa;
  const float m11r = cb*ca,  m11i = -sb*sa;
  gt[8*t+0] = cg*m00r + sg*m00i;  gt[8*t+1] = cg*m00i - sg*m00r;
  gt[8*t+2] = cg*m01r + sg*m01i;  gt[8*t+3] = cg*m01i - sg*m01r;
  gt[8*t+4] = cg*m10r - sg*m10i;  gt[8*t+5] = cg*m10i + sg*m10r;
  gt[8*t+6] = cg*m11r - sg*m11i;  gt[8*t+7] = cg*m11i + sg*m11r;
  gt[80+2*t] = cosf(hd); gt[81+2*t] = sinf(hd);
}

__global__ void __launch_bounds__(NT)   // NO waves-per-EU hint (R3/R6 spill lesson)
qqk_kernel(const float* __restrict__ x, const float* __restrict__ gt,
           float* __restrict__ out)
{
  __shared__ __align__(16) f2 smem[4096];   // one 1024-f2 state buffer per wave
  const int t = threadIdx.x, wave = t >> 6, lane = t & 63;
  f2* bb = smem + (wave << 10);
  const f2* g2  = (const f2*)gt;
  const f2* gry = (const f2*)(gt + 80);
  const size_t e = (size_t)blockIdx.x * 4 + wave;
  const float* xg = x + e * NFEAT;

  const int aA = (lane << 1) ^ ((lane >> 2) & 14);                   // swz2(lane<<1)
  const int aB = ((lane >> 3) << 7) | ((lane & 7) << 1);             // swz2 = identity here
  const int aC = (lane << 4) ^ ((lane << 1) & 14);                   // swz2(lane<<4)

  // twiddle constants T(e) = exp(+2pi i e/1024)
  const f2 T1c   = { 0.9999811752826011f, 0.0061358846491545f };
  const f2 T2c   = { 0.9999247018391445f, 0.0122715382857199f };
  const f2 T4c   = { 0.9996988186962042f, 0.0245412285229123f };
  const f2 T8c   = { 0.9987954562051724f, 0.0490676743274180f };
  const f2 T16c  = { 0.9951847266721969f, 0.0980171403295606f };
  const f2 T32c  = { 0.9807852804032304f, 0.1950903220161283f };
  const float c45 = 0.7071067811865476f, c22 = 0.9238795325112867f, s22 = 0.3826834323650898f;
  const f2 T64c  = { c22, s22 };
  const f2 T128c = { c45, c45 };

  f2 xv[16];
  // ---- P0: global float2 load + norm + gates q0,q1,q2 (bits 9,8,7) and q9 (bit 0); write A' ----
  float ss = 0.f;
  #pragma unroll
  for (int k = 0; k < 6; ++k){
    const float2 v = *(const float2*)(xg + (k << 7) + (lane << 1));
    xv[2*k] = f2{v.x, 0.f}; xv[2*k+1] = f2{v.y, 0.f};
    ss += v.x*v.x + v.y*v.y;
  }
  #pragma unroll
  for (int m = 12; m < 16; ++m) xv[m] = f2{0.f, 0.f};
  ss = dpp_add<0xB1>(ss); ss = dpp_add<0x4E>(ss);
  ss += __shfl_xor(ss, 4); ss += __shfl_xor(ss, 8); ss += __shfl_xor(ss, 16); ss += __shfl_xor(ss, 32);
  const float invn = 1.0f / fmaxf(sqrtf(ss), 1e-8f);
  #pragma unroll
  for (int m = 0; m < 12; ++m) xv[m].x *= invn;
  gate_on<8>(xv, g2+0); gate_on<4>(xv, g2+4); gate_on<2>(xv, g2+8); gate_on<1>(xv, g2+36);
  wrA(bb, aA, xv);
  MEMFENCE();
  // ---- P1: gates q3,q4,q5 (bits 6,5,4), layout B' ----
  rdB(bb, aB, xv);
  gate_on<8>(xv, g2+12); gate_on<4>(xv, g2+16); gate_on<2>(xv, g2+20);
  wrB(bb, aB, xv);
  MEMFENCE();
  // ---- P2: gates q6,q7,q8 (bits 3,2,1), layout C' ----
  rdC(bb, aC, xv);
  gate_on<8>(xv, g2+24); gate_on<4>(xv, g2+28); gate_on<2>(xv, g2+32);
  wrC(bb, aC, xv);
  MEMFENCE();
  // ---- P3: CNOT-ring gather (to C' slots) + RY q6,q7,q8,q9; write C' ----
  { const int ag = swz2(cnot_perm(lane << 4));
    #pragma unroll
    for (int m = 0; m < 16; ++m) xv[m] = bb[ag ^ swz2(cnot_perm(m))];
  }
  MEMFENCE();   // all gather reads precede the overwrites below (in-order DS)
  ry_on<8>(xv, gry[6]); ry_on<4>(xv, gry[7]); ry_on<2>(xv, gry[8]); ry_on<1>(xv, gry[9]);
  wrC(bb, aC, xv);
  MEMFENCE();
  // ---- P4: RY q3,q4,q5, layout B' ----
  rdB(bb, aB, xv);
  ry_on<8>(xv, gry[3]); ry_on<4>(xv, gry[4]); ry_on<2>(xv, gry[5]);
  wrB(bb, aB, xv);
  MEMFENCE();
  // ---- P5: RY q0,q1,q2 FUSED with FFT stages bits 9,8,7 (layout A') ----
  rdA(bb, aA, xv);
  ry_on<8>(xv, gry[0]); ry_on<4>(xv, gry[1]); ry_on<2>(xv, gry[2]);
  { float sa, ca; __sincosf((float)lane * 1.2271846303085130e-2f, &sa, &ca);  // BT = T(2*lane)
    const f2 BT = {ca, sa};
    const f2 BT2 = pk_cmul(BT, BT);
    const f2 BT4 = pk_cmul(BT2, BT2);
    f2 t9[8];
    t9[0] = BT;               t9[1] = pk_cmul(BT, T1c);
    t9[2] = pk_cmul(BT, T128c); t9[3] = pk_cmul(t9[1], T128c);
    t9[4] = rot90(t9[0]); t9[5] = rot90(t9[1]); t9[6] = rot90(t9[2]); t9[7] = rot90(t9[3]);
    #pragma unroll
    for (int m = 0; m < 8; ++m) bfly(xv[m], xv[m+8], t9[m]);        // stage bit 9
    f2 u[4];
    u[0] = BT2; u[1] = pk_cmul(BT2, T2c); u[2] = rot90(u[0]); u[3] = rot90(u[1]);
    #pragma unroll
    for (int m = 0; m < 16; ++m) if (!(m & 4)) bfly(xv[m], xv[m|4], u[m & 3]);   // bit 8
    f2 v2[2];
    v2[0] = BT4; v2[1] = pk_cmul(BT4, T4c);
    #pragma unroll
    for (int m = 0; m < 16; ++m) if (!(m & 2)) bfly(xv[m], xv[m|2], v2[m & 1]);  // bit 7
  }
  wrA(bb, aA, xv);
  MEMFENCE();
  // ---- P6: FFT stages bits 6,5,4 (layout B') ----
  rdB(bb, aB, xv);
  { float sa, ca; __sincosf((float)(lane & 7) * 9.8174770424681035e-2f, &sa, &ca);  // CT = T(16*lane_l)
    const f2 CT = {ca, sa};
    const f2 CT2 = pk_cmul(CT, CT);
    const f2 CT4 = pk_cmul(CT2, CT2);
    f2 t6[8];
    t6[0] = CT;               t6[1] = pk_cmul(CT, T8c);
    t6[2] = pk_cmul(CT, T128c); t6[3] = pk_cmul(t6[1], T128c);
    t6[4] = rot90(t6[0]); t6[5] = rot90(t6[1]); t6[6] = rot90(t6[2]); t6[7] = rot90(t6[3]);
    #pragma unroll
    for (int m = 0; m < 8; ++m) bfly(xv[m], xv[m+8], t6[m]);        // stage bit 6
    f2 u[4];
    u[0] = CT2; u[1] = pk_cmul(CT2, T16c); u[2] = rot90(u[0]); u[3] = rot90(u[1]);
    #pragma unroll
    for (int m = 0; m < 16; ++m) if (!(m & 4)) bfly(xv[m], xv[m|4], u[m & 3]);   // bit 5
    f2 v2[2];
    v2[0] = CT4; v2[1] = pk_cmul(CT4, T32c);
    #pragma unroll
    for (int m = 0; m < 16; ++m) if (!(m & 2)) bfly(xv[m], xv[m|2], v2[m & 1]);  // bit 4
  }
  wrB(bb, aB, xv);
  MEMFENCE();
  // ---- P7: FFT stages bits 3,2,1,0 (all-constant twiddles) + expectations q0..q3 (layout C') ----
  rdC(bb, aC, xv);
  // stage bit 3: tw = T(64*m)
  bfly1(xv[0], xv[8]);
  bfly (xv[1], xv[9],  T64c);
  bfly (xv[2], xv[10], T128c);
  bfly (xv[3], xv[11], f2{ s22, c22});
  bflyI(xv[4], xv[12]);
  bfly (xv[5], xv[13], f2{-s22, c22});
  bfly (xv[6], xv[14], f2{-c45, c45});
  bfly (xv[7], xv[15], f2{-c22, s22});
  // stage bit 2: tw = T(128*(m&3))
  #pragma unroll
  for (int m = 0; m < 16; ++m) if (!(m & 4)){
    const int s = m & 3;
    if      (s == 0) bfly1(xv[m], xv[m|4]);
    else if (s == 1) bfly (xv[m], xv[m|4], T128c);
    else if (s == 2) bflyI(xv[m], xv[m|4]);
    else             bfly (xv[m], xv[m|4], f2{-c45, c45});
  }
  // stage bit 1: tw = {1, i}
  #pragma unroll
  for (int m = 0; m < 16; ++m) if (!(m & 2)){
    if (m & 1) bflyI(xv[m], xv[m|2]); else bfly1(xv[m], xv[m|2]);
  }
  // stage bit 0: tw = 1
  #pragma unroll
  for (int m = 0; m < 16; m += 2) bfly1(xv[m], xv[m+1]);
  wrC(bb, aC, xv);
  // expectations: qubit q <-> g-bit q; in-reg g-bits 3..0 -> qubits 3,2,1,0
  f2 xrxi[10];
  xrxi[0] = pairsum16<1>(xv); xrxi[1] = pairsum16<2>(xv);
  xrxi[2] = pairsum16<4>(xv); xrxi[3] = pairsum16<8>(xv);
  float S = 0.f, z0 = 0.f, z1 = 0.f, z2 = 0.f, z3 = 0.f;
  #pragma unroll
  for (int m = 0; m < 16; ++m){
    const f2 q = xv[m]*xv[m]; const float n = q.x + q.y;
    S += n;
    z0 += (m & 1) ? -n : n;  z1 += (m & 2) ? -n : n;
    z2 += (m & 4) ? -n : n;  z3 += (m & 8) ? -n : n;
  }
  MEMFENCE();
  // ---- P8 (read-only, layout A'): g-bits {9,8,7} -> qubits 9,8,7 ----
  rdA(bb, aA, xv);
  xrxi[9] = pairsum16<8>(xv); xrxi[8] = pairsum16<4>(xv); xrxi[7] = pairsum16<2>(xv);
  // ---- P9 (read-only, layout B'): g-bits {6,5,4} -> qubits 6,5,4 ----
  rdB(bb, aB, xv);
  xrxi[6] = pairsum16<8>(xv); xrxi[5] = pairsum16<4>(xv); xrxi[4] = pairsum16<2>(xv);
  MEMFENCE();   // all state reads precede the reduction-row overwrite

  // ---- Walsh-Hadamard over lane bits on S -> Z4..Z9 (lane bit k = g-bit 4+k = qubit 4+k) ----
  float d0, d1, d2, d3, d4, d5;
  { float s = S, wv;
    wv = dpp_mov<0xB1>(s); d0 = (lane & 1)  ? (wv - s) : (s - wv); s += wv;
    wv = dpp_mov<0x4E>(s); d1 = (lane & 2)  ? (wv - s) : (s - wv); s += wv;
    wv = __shfl_xor(s, 4);  d2 = (lane & 4)  ? (wv - s) : (s - wv); s += wv;
    wv = __shfl_xor(s, 8);  d3 = (lane & 8)  ? (wv - s) : (s - wv); s += wv;
    wv = __shfl_xor(s, 16); d4 = (lane & 16) ? (wv - s) : (s - wv); s += wv;
    wv = __shfl_xor(s, 32); d5 = (lane & 32) ? (wv - s) : (s - wv); s += wv;
    d0 = dpp_add<0x4E>(d0); d0 += __shfl_xor(d0, 4); d0 += __shfl_xor(d0, 8); d0 += __shfl_xor(d0, 16); d0 += __shfl_xor(d0, 32);
    d1 += __shfl_xor(d1, 4); d1 += __shfl_xor(d1, 8); d1 += __shfl_xor(d1, 16); d1 += __shfl_xor(d1, 32);
    d2 += __shfl_xor(d2, 8); d2 += __shfl_xor(d2, 16); d2 += __shfl_xor(d2, 32);
    d3 += __shfl_xor(d3, 16); d3 += __shfl_xor(d3, 32);
    d4 += __shfl_xor(d4, 32);
  }

  // ---- quad pre-sum via DPP, then 24x16 float row transpose in dead state LDS (R7-proven) ----
  #pragma unroll
  for (int q = 0; q < 10; ++q){
    xrxi[q].x = dpp_add<0x4E>(dpp_add<0xB1>(xrxi[q].x));
    xrxi[q].y = dpp_add<0x4E>(dpp_add<0xB1>(xrxi[q].y));
  }
  z0 = dpp_add<0x4E>(dpp_add<0xB1>(z0));
  z1 = dpp_add<0x4E>(dpp_add<0xB1>(z1));
  z2 = dpp_add<0x4E>(dpp_add<0xB1>(z2));
  z3 = dpp_add<0x4E>(dpp_add<0xB1>(z3));
  float* rb = (float*)bb;
  const int g = lane >> 2;
  if ((lane & 3) == 0){
    #pragma unroll
    for (int q = 0; q < 10; ++q){ rb[q*16 + g] = xrxi[q].x; rb[(10+q)*16 + g] = xrxi[q].y; }
    rb[20*16 + g] = z0; rb[21*16 + g] = z1; rb[22*16 + g] = z2; rb[23*16 + g] = z3;
  }
  MEMFENCE();   // row writes precede row reads (same-wave in-order DS)
  float* ob = out + e * 30;
  if (lane < 24){
    float acc = 0.f;
    #pragma unroll
    for (int gg = 0; gg < 16; ++gg) acc += rb[lane*16 + gg];
    ob[lane] = acc * ((lane < 20) ? (2.0f/1024.0f) : (1.0f/1024.0f));
  }
  if (lane == 0){
    const float zs = 1.0f/1024.0f;
    ob[24] = d0*zs; ob[25] = d1*zs; ob[26] = d2*zs;
    ob[27] = d3*zs; ob[28] = d4*zs; ob[29] = d5*zs;
  }
}

extern "C" void kernel_launch(void* const* d_in, const int* in_sizes, int n_in,
                              void* d_out, int out_size, void* d_ws, size_t ws_size,
                              hipStream_t stream) {
  const float* x = (const float*)d_in[0];
  const float* w = (const float*)d_in[1];
  float* out = (float*)d_out;
  float* gt  = (float*)d_ws;           // 100 floats of gate tables
  const int B = in_sizes[0] / NFEAT;   // 8192
  gate_prep<<<1, 16, 0, stream>>>(w, gt);
  qqk_kernel<<<B/4, NT, 0, stream>>>(x, gt, out);
}

// Round 12
// 44.621 us; speedup vs baseline: 2.1172x; 1.0221x over previous
//
#include <hip/hip_runtime.h>
#include <math.h>

#define NFEAT 768
#define NT    256   // 4 waves/block, 1 wave = 1 element, ZERO barriers (R7/R10-proven shape)

typedef float f2 __attribute__((ext_vector_type(2)));
#define MEMFENCE() asm volatile("" ::: "memory")

// bit0-preserving GF2-linear swizzle: addr bits 3..1 ^= index bits 6..4.
__device__ __forceinline__ int swz2(int j){ return j ^ ((j >> 3) & 0xE); }

// Composite of the CNOT ring CNOT(0,1),...,CNOT(9,0): s_after[j] = s_before[perm(j)]. GF2-linear.
__device__ __forceinline__ int cnot_perm(int j){
  int i = j;
  i ^= ((i >> 0) & 1) << 9;
  i ^= ((i >> 1) & 1) << 0;
  i ^= ((i >> 2) & 1) << 1;
  i ^= ((i >> 3) & 1) << 2;
  i ^= ((i >> 4) & 1) << 3;
  i ^= ((i >> 5) & 1) << 4;
  i ^= ((i >> 6) & 1) << 5;
  i ^= ((i >> 7) & 1) << 6;
  i ^= ((i >> 8) & 1) << 7;
  i ^= ((i >> 9) & 1) << 8;
  return i;
}

// ---- DPP cross-lane (VALU pipe): quad_perm xor1=0xB1, xor2=0x4E ----
template<int CTRL>
__device__ __forceinline__ float dpp_mov(float x){
  return __builtin_bit_cast(float,
    __builtin_amdgcn_update_dpp(0, __builtin_bit_cast(int, x), CTRL, 0xF, 0xF, true));
}
template<int CTRL>
__device__ __forceinline__ float dpp_add(float x){ return x + dpp_mov<CTRL>(x); }

// ---- packed-f32 complex primitives (VOP3P, verified R5/R7/R10) ----
__device__ __forceinline__ f2 pk_cmul(f2 s, f2 v){
  f2 d;
  asm("v_pk_mul_f32 %0, %1, %2 op_sel:[0,0] op_sel_hi:[0,1]\n\t"
      "v_pk_fma_f32 %0, %1, %2, %0 op_sel:[1,1,0] op_sel_hi:[1,0,1] neg_lo:[0,1,0]"
      : "=&v"(d) : "v"(s), "v"(v));
  return d;
}
__device__ __forceinline__ f2 pk_cfma(f2 s, f2 v, f2 acc){
  f2 d;
  asm("v_pk_fma_f32 %0, %2, %3, %1 op_sel:[0,0,0] op_sel_hi:[0,1,1]\n\t"
      "v_pk_fma_f32 %0, %2, %3, %0 op_sel:[1,1,0] op_sel_hi:[1,0,1] neg_lo:[0,1,0]"
      : "=&v"(d) : "v"(acc), "v"(s), "v"(v));
  return d;
}
// d = acc + (a.r*b.i, -a.i*b.r)
__device__ __forceinline__ f2 pk_cross(f2 a, f2 b, f2 acc){
  f2 d;
  asm("v_pk_fma_f32 %0, %2, %3, %1 op_sel:[0,1,0] op_sel_hi:[1,0,1] neg_hi:[1,0,0]"
      : "=&v"(d) : "v"(acc), "v"(a), "v"(b));
  return d;
}
__device__ __forceinline__ void pk_ry(f2 cs, f2& a, f2& b){
  f2 t1, t2, na, nb;
  asm("v_pk_mul_f32 %0, %2, %3 op_sel:[1,0] op_sel_hi:[1,1] neg_lo:[1,0] neg_hi:[1,0]\n\t"
      "v_pk_mul_f32 %1, %2, %4 op_sel:[1,0] op_sel_hi:[1,1]"
      : "=&v"(t1), "=&v"(t2) : "v"(cs), "v"(b), "v"(a));
  asm("v_pk_fma_f32 %0, %2, %3, %4 op_sel:[0,0,0] op_sel_hi:[0,1,1]\n\t"
      "v_pk_fma_f32 %1, %2, %5, %6 op_sel:[0,0,0] op_sel_hi:[0,1,1]"
      : "=&v"(na), "=&v"(nb) : "v"(cs), "v"(a), "v"(t1), "v"(b), "v"(t2));
  a = na; b = nb;
}
__device__ __forceinline__ void gateU(const f2* g, f2& a, f2& b){
  const f2 na = pk_cfma(g[1], b, pk_cmul(g[0], a));
  const f2 nb = pk_cfma(g[3], b, pk_cmul(g[2], a));
  a = na; b = nb;
}
__device__ __forceinline__ f2 rot90(f2 v){ return f2{-v.y, v.x}; }
__device__ __forceinline__ void bfly(f2& a, f2& b, f2 tw){
  const f2 u = a + b, v = a - b;
  a = u; b = pk_cmul(tw, v);
}
__device__ __forceinline__ void bfly1(f2& a, f2& b){
  const f2 u = a + b, v = a - b; a = u; b = v;
}
__device__ __forceinline__ void bflyI(f2& a, f2& b){
  const f2 u = a + b, v = a - b; a = u; b = f2{-v.y, v.x};
}

template<int MASK>
__device__ __forceinline__ void gate_on(f2* xv, const f2* g){
  #pragma unroll
  for (int m = 0; m < 16; ++m) if (!(m & MASK)) gateU(g, xv[m], xv[m|MASK]);
}
template<int MASK>
__device__ __forceinline__ void ry_on(f2* xv, const f2 cs){
  #pragma unroll
  for (int m = 0; m < 16; ++m) if (!(m & MASK)) pk_ry(cs, xv[m], xv[m|MASK]);
}
template<int MASK>
__device__ __forceinline__ f2 pairsum16(const f2* z){
  f2 rp = {0.f, 0.f}, ip = {0.f, 0.f};
  #pragma unroll
  for (int m = 0; m < 16; ++m) if (!(m & MASK)){
    rp = z[m]*z[m|MASK] + rp;
    ip = pk_cross(z[m], z[m|MASK], ip);
  }
  return f2{ rp.x + rp.y, ip.x + ip.y };
}

// ---- b128-paired LDS I/O (layouts A'/B'/C' as in R10) ----
__device__ __forceinline__ void rdA(const f2* bb, int a0, f2* xv){
  #pragma unroll
  for (int k = 0; k < 8; ++k){
    const float4 v = *(const float4*)(bb + (a0 ^ (k << 7)));
    xv[2*k] = f2{v.x, v.y}; xv[2*k+1] = f2{v.z, v.w};
  }
}
__device__ __forceinline__ void wrA(f2* bb, int a0, const f2* xv){
  #pragma unroll
  for (int k = 0; k < 8; ++k)
    *(float4*)(bb + (a0 ^ (k << 7))) = make_float4(xv[2*k].x, xv[2*k].y, xv[2*k+1].x, xv[2*k+1].y);
}
__device__ __forceinline__ void rdB(const f2* bb, int a0, f2* xv){
  #pragma unroll
  for (int k = 0; k < 8; ++k){
    const float4 v = *(const float4*)(bb + (a0 ^ ((k << 4) | (k << 1))));
    xv[2*k] = f2{v.x, v.y}; xv[2*k+1] = f2{v.z, v.w};
  }
}
__device__ __forceinline__ void wrB(f2* bb, int a0, const f2* xv){
  #pragma unroll
  for (int k = 0; k < 8; ++k)
    *(float4*)(bb + (a0 ^ ((k << 4) | (k << 1)))) = make_float4(xv[2*k].x, xv[2*k].y, xv[2*k+1].x, xv[2*k+1].y);
}
__device__ __forceinline__ void rdC(const f2* bb, int a0, f2* xv){
  #pragma unroll
  for (int k = 0; k < 8; ++k){
    const float4 v = *(const float4*)(bb + (a0 ^ (k << 1)));
    xv[2*k] = f2{v.x, v.y}; xv[2*k+1] = f2{v.z, v.w};
  }
}
__device__ __forceinline__ void wrC(f2* bb, int a0, const f2* xv){
  #pragma unroll
  for (int k = 0; k < 8; ++k)
    *(float4*)(bb + (a0 ^ (k << 1))) = make_float4(xv[2*k].x, xv[2*k].y, xv[2*k+1].x, xv[2*k+1].y);
}

__global__ void gate_prep(const float* __restrict__ w, float* __restrict__ gt){
  const int t = threadIdx.x;
  if (t >= 10) return;
  const float ha = 0.5f*w[t*4+0], hb = 0.5f*w[t*4+1];
  const float hg = 0.5f*w[t*4+2], hd = 0.5f*w[t*4+3];
  const float ca = cosf(ha), sa = sinf(ha);
  const float cb = cosf(hb), sb = sinf(hb);
  const float cg = cosf(hg), sg = sinf(hg);
  const float m00r = cb*ca, m00i =  sb*sa;
  const float m01r = -sb*ca, m01i = -cb*sa;
  const float m10r =  sb*ca, m10i = -cb*sa;
  const float m11r = cb*ca,  m11i = -sb*sa;
  gt[8*t+0] = cg*m00r + sg*m00i;  gt[8*t+1] = cg*m00i - sg*m00r;
  gt[8*t+2] = cg*m01r + sg*m01i;  gt[8*t+3] = cg*m01i - sg*m01r;
  gt[8*t+4] = cg*m10r - sg*m10i;  gt[8*t+5] = cg*m10i + sg*m10r;
  gt[8*t+6] = cg*m11r - sg*m11i;  gt[8*t+7] = cg*m11i + sg*m11r;
  gt[80+2*t] = cosf(hd); gt[81+2*t] = sinf(hd);
}

__global__ void __launch_bounds__(NT)   // NO waves-per-EU hint (R3/R6 spill lesson)
qqk_kernel(const float* __restrict__ x, const float* __restrict__ gt,
           float* __restrict__ out)
{
  __shared__ __align__(16) f2 smem[4096];   // one 1024-f2 state buffer per wave
  const int t = threadIdx.x, wave = t >> 6, lane = t & 63;
  f2* bb = smem + (wave << 10);
  const f2* g2  = (const f2*)gt;
  const f2* gry = (const f2*)(gt + 80);
  const size_t e = (size_t)blockIdx.x * 4 + wave;
  const float* xg = x + e * NFEAT;

  const int aA = (lane << 1) ^ ((lane >> 2) & 14);
  const int aB = ((lane >> 3) << 7) | ((lane & 7) << 1);
  const int aC = (lane << 4) ^ ((lane << 1) & 14);

  // twiddle constants T(e) = exp(+2pi i e/1024)
  const f2 T1c   = { 0.9999811752826011f, 0.0061358846491545f };
  const f2 T2c   = { 0.9999247018391445f, 0.0122715382857199f };
  const f2 T4c   = { 0.9996988186962042f, 0.0245412285229123f };
  const f2 T8c   = { 0.9987954562051724f, 0.0490676743274180f };
  const f2 T16c  = { 0.9951847266721969f, 0.0980171403295606f };
  const f2 T32c  = { 0.9807852804032304f, 0.1950903220161283f };
  const float c45 = 0.7071067811865476f, c22 = 0.9238795325112867f, s22 = 0.3826834323650898f;
  const f2 T64c  = { c22, s22 };
  const f2 T128c = { c45, c45 };

  f2 xrxi[10];
  f2 xv[16];
  // ---- P0: global float2 load + norm + gates q0,q1,q2 (bits 9,8,7) and q9 (bit 0); write A' ----
  float ss = 0.f;
  #pragma unroll
  for (int k = 0; k < 6; ++k){
    const float2 v = *(const float2*)(xg + (k << 7) + (lane << 1));
    xv[2*k] = f2{v.x, 0.f}; xv[2*k+1] = f2{v.y, 0.f};
    ss += v.x*v.x + v.y*v.y;
  }
  #pragma unroll
  for (int m = 12; m < 16; ++m) xv[m] = f2{0.f, 0.f};
  ss = dpp_add<0xB1>(ss); ss = dpp_add<0x4E>(ss);
  ss += __shfl_xor(ss, 4); ss += __shfl_xor(ss, 8); ss += __shfl_xor(ss, 16); ss += __shfl_xor(ss, 32);
  const float invn = 1.0f / fmaxf(sqrtf(ss), 1e-8f);
  #pragma unroll
  for (int m = 0; m < 12; ++m) xv[m].x *= invn;
  gate_on<8>(xv, g2+0); gate_on<4>(xv, g2+4); gate_on<2>(xv, g2+8); gate_on<1>(xv, g2+36);
  wrA(bb, aA, xv);
  MEMFENCE();
  // ---- P1: gates q3,q4,q5 (bits 6,5,4), layout B' ----
  rdB(bb, aB, xv);
  gate_on<8>(xv, g2+12); gate_on<4>(xv, g2+16); gate_on<2>(xv, g2+20);
  wrB(bb, aB, xv);
  MEMFENCE();
  // ---- P2: gates q6,q7,q8 (bits 3,2,1), layout C' ----
  rdC(bb, aC, xv);
  gate_on<8>(xv, g2+24); gate_on<4>(xv, g2+28); gate_on<2>(xv, g2+32);
  wrC(bb, aC, xv);
  MEMFENCE();
  // ---- P3: CNOT-ring gather (to C' slots) + RY q6,q7,q8,q9; write C' ----
  { const int ag = swz2(cnot_perm(lane << 4));
    #pragma unroll
    for (int m = 0; m < 16; ++m) xv[m] = bb[ag ^ swz2(cnot_perm(m))];
  }
  MEMFENCE();   // all gather reads precede the overwrites below (in-order DS)
  ry_on<8>(xv, gry[6]); ry_on<4>(xv, gry[7]); ry_on<2>(xv, gry[8]); ry_on<1>(xv, gry[9]);
  wrC(bb, aC, xv);
  MEMFENCE();
  // ---- P4: RY q3,q4,q5, layout B' ----
  rdB(bb, aB, xv);
  ry_on<8>(xv, gry[3]); ry_on<4>(xv, gry[4]); ry_on<2>(xv, gry[5]);
  wrB(bb, aB, xv);
  MEMFENCE();
  // ---- P5: RY q0,q1,q2 + FFT stages bits 9,8,7 + EXPECTATIONS q9,q8,q7 (layout A') ----
  // Remaining stages act on bits 6..0 only; each unnormalized bfly stage has
  // B^dag B = 2I, so a pairsum taken after 3 of 10 stages is missing 2^7.
  rdA(bb, aA, xv);
  ry_on<8>(xv, gry[0]); ry_on<4>(xv, gry[1]); ry_on<2>(xv, gry[2]);
  { float sa, ca; __sincosf((float)lane * 1.2271846303085130e-2f, &sa, &ca);  // BT = T(2*lane)
    const f2 BT = {ca, sa};
    const f2 BT2 = pk_cmul(BT, BT);
    const f2 BT4 = pk_cmul(BT2, BT2);
    f2 t9[8];
    t9[0] = BT;               t9[1] = pk_cmul(BT, T1c);
    t9[2] = pk_cmul(BT, T128c); t9[3] = pk_cmul(t9[1], T128c);
    t9[4] = rot90(t9[0]); t9[5] = rot90(t9[1]); t9[6] = rot90(t9[2]); t9[7] = rot90(t9[3]);
    #pragma unroll
    for (int m = 0; m < 8; ++m) bfly(xv[m], xv[m+8], t9[m]);        // stage bit 9
    f2 u[4];
    u[0] = BT2; u[1] = pk_cmul(BT2, T2c); u[2] = rot90(u[0]); u[3] = rot90(u[1]);
    #pragma unroll
    for (int m = 0; m < 16; ++m) if (!(m & 4)) bfly(xv[m], xv[m|4], u[m & 3]);   // bit 8
    f2 v2[2];
    v2[0] = BT4; v2[1] = pk_cmul(BT4, T4c);
    #pragma unroll
    for (int m = 0; m < 16; ++m) if (!(m & 2)) bfly(xv[m], xv[m|2], v2[m & 1]);  // bit 7
  }
  xrxi[9] = pairsum16<8>(xv) * 128.0f;   // missing 2^7 from remaining 7 stages
  xrxi[8] = pairsum16<4>(xv) * 128.0f;
  xrxi[7] = pairsum16<2>(xv) * 128.0f;
  wrA(bb, aA, xv);
  MEMFENCE();
  // ---- P6: FFT stages bits 6,5,4 + EXPECTATIONS q6,q5,q4 (layout B') ----
  rdB(bb, aB, xv);
  { float sa, ca; __sincosf((float)(lane & 7) * 9.8174770424681035e-2f, &sa, &ca);  // CT = T(16*lane_l)
    const f2 CT = {ca, sa};
    const f2 CT2 = pk_cmul(CT, CT);
    const f2 CT4 = pk_cmul(CT2, CT2);
    f2 t6[8];
    t6[0] = CT;               t6[1] = pk_cmul(CT, T8c);
    t6[2] = pk_cmul(CT, T128c); t6[3] = pk_cmul(t6[1], T128c);
    t6[4] = rot90(t6[0]); t6[5] = rot90(t6[1]); t6[6] = rot90(t6[2]); t6[7] = rot90(t6[3]);
    #pragma unroll
    for (int m = 0; m < 8; ++m) bfly(xv[m], xv[m+8], t6[m]);        // stage bit 6
    f2 u[4];
    u[0] = CT2; u[1] = pk_cmul(CT2, T16c); u[2] = rot90(u[0]); u[3] = rot90(u[1]);
    #pragma unroll
    for (int m = 0; m < 16; ++m) if (!(m & 4)) bfly(xv[m], xv[m|4], u[m & 3]);   // bit 5
    f2 v2[2];
    v2[0] = CT4; v2[1] = pk_cmul(CT4, T32c);
    #pragma unroll
    for (int m = 0; m < 16; ++m) if (!(m & 2)) bfly(xv[m], xv[m|2], v2[m & 1]);  // bit 4
  }
  xrxi[6] = pairsum16<8>(xv) * 16.0f;    // missing 2^4 from remaining 4 stages
  xrxi[5] = pairsum16<4>(xv) * 16.0f;
  xrxi[4] = pairsum16<2>(xv) * 16.0f;
  wrB(bb, aB, xv);
  MEMFENCE();
  // ---- P7: FFT stages bits 3,2,1,0 + expectations q0..q3 + probabilities (layout C', NO write-back) ----
  rdC(bb, aC, xv);
  // stage bit 3: tw = T(64*m)
  bfly1(xv[0], xv[8]);
  bfly (xv[1], xv[9],  T64c);
  bfly (xv[2], xv[10], T128c);
  bfly (xv[3], xv[11], f2{ s22, c22});
  bflyI(xv[4], xv[12]);
  bfly (xv[5], xv[13], f2{-s22, c22});
  bfly (xv[6], xv[14], f2{-c45, c45});
  bfly (xv[7], xv[15], f2{-c22, s22});
  // stage bit 2: tw = T(128*(m&3))
  #pragma unroll
  for (int m = 0; m < 16; ++m) if (!(m & 4)){
    const int s = m & 3;
    if      (s == 0) bfly1(xv[m], xv[m|4]);
    else if (s == 1) bfly (xv[m], xv[m|4], T128c);
    else if (s == 2) bflyI(xv[m], xv[m|4]);
    else             bfly (xv[m], xv[m|4], f2{-c45, c45});
  }
  // stage bit 1: tw = {1, i}
  #pragma unroll
  for (int m = 0; m < 16; ++m) if (!(m & 2)){
    if (m & 1) bflyI(xv[m], xv[m|2]); else bfly1(xv[m], xv[m|2]);
  }
  // stage bit 0: tw = 1
  #pragma unroll
  for (int m = 0; m < 16; m += 2) bfly1(xv[m], xv[m+1]);
  xrxi[0] = pairsum16<1>(xv); xrxi[1] = pairsum16<2>(xv);
  xrxi[2] = pairsum16<4>(xv); xrxi[3] = pairsum16<8>(xv);
  float S = 0.f, z0 = 0.f, z1 = 0.f, z2 = 0.f, z3 = 0.f;
  #pragma unroll
  for (int m = 0; m < 16; ++m){
    const f2 q = xv[m]*xv[m]; const float n = q.x + q.y;
    S += n;
    z0 += (m & 1) ? -n : n;  z1 += (m & 2) ? -n : n;
    z2 += (m & 4) ? -n : n;  z3 += (m & 8) ? -n : n;
  }
  MEMFENCE();   // all state reads precede the reduction-row overwrite

  // ---- Walsh-Hadamard over lane bits on S -> Z4..Z9 ----
  float d0, d1, d2, d3, d4, d5;
  { float s = S, wv;
    wv = dpp_mov<0xB1>(s); d0 = (lane & 1)  ? (wv - s) : (s - wv); s += wv;
    wv = dpp_mov<0x4E>(s); d1 = (lane & 2)  ? (wv - s) : (s - wv); s += wv;
    wv = __shfl_xor(s, 4);  d2 = (lane & 4)  ? (wv - s) : (s - wv); s += wv;
    wv = __shfl_xor(s, 8);  d3 = (lane & 8)  ? (wv - s) : (s - wv); s += wv;
    wv = __shfl_xor(s, 16); d4 = (lane & 16) ? (wv - s) : (s - wv); s += wv;
    wv = __shfl_xor(s, 32); d5 = (lane & 32) ? (wv - s) : (s - wv); s += wv;
    d0 = dpp_add<0x4E>(d0); d0 += __shfl_xor(d0, 4); d0 += __shfl_xor(d0, 8); d0 += __shfl_xor(d0, 16); d0 += __shfl_xor(d0, 32);
    d1 += __shfl_xor(d1, 4); d1 += __shfl_xor(d1, 8); d1 += __shfl_xor(d1, 16); d1 += __shfl_xor(d1, 32);
    d2 += __shfl_xor(d2, 8); d2 += __shfl_xor(d2, 16); d2 += __shfl_xor(d2, 32);
    d3 += __shfl_xor(d3, 16); d3 += __shfl_xor(d3, 32);
    d4 += __shfl_xor(d4, 32);
  }

  // ---- quad pre-sum via DPP, then 24x17-stride float row transpose (conflict-free) ----
  #pragma unroll
  for (int q = 0; q < 10; ++q){
    xrxi[q].x = dpp_add<0x4E>(dpp_add<0xB1>(xrxi[q].x));
    xrxi[q].y = dpp_add<0x4E>(dpp_add<0xB1>(xrxi[q].y));
  }
  z0 = dpp_add<0x4E>(dpp_add<0xB1>(z0));
  z1 = dpp_add<0x4E>(dpp_add<0xB1>(z1));
  z2 = dpp_add<0x4E>(dpp_add<0xB1>(z2));
  z3 = dpp_add<0x4E>(dpp_add<0xB1>(z3));
  float* rb = (float*)bb;
  const int g = lane >> 2;
  if ((lane & 3) == 0){
    #pragma unroll
    for (int q = 0; q < 10; ++q){ rb[q*17 + g] = xrxi[q].x; rb[(10+q)*17 + g] = xrxi[q].y; }
    rb[20*17 + g] = z0; rb[21*17 + g] = z1; rb[22*17 + g] = z2; rb[23*17 + g] = z3;
  }
  MEMFENCE();   // row writes precede row reads (same-wave in-order DS)
  float* ob = out + e * 30;
  if (lane < 24){
    float acc = 0.f;
    #pragma unroll
    for (int gg = 0; gg < 16; ++gg) acc += rb[lane*17 + gg];
    ob[lane] = acc * ((lane < 20) ? (2.0f/1024.0f) : (1.0f/1024.0f));
  }
  if (lane == 0){
    const float zs = 1.0f/1024.0f;
    ob[24] = d0*zs; ob[25] = d1*zs; ob[26] = d2*zs;
    ob[27] = d3*zs; ob[28] = d4*zs; ob[29] = d5*zs;
  }
}

extern "C" void kernel_launch(void* const* d_in, const int* in_sizes, int n_in,
                              void* d_out, int out_size, void* d_ws, size_t ws_size,
                              hipStream_t stream) {
  const float* x = (const float*)d_in[0];
  const float* w = (const float*)d_in[1];
  float* out = (float*)d_out;
  float* gt  = (float*)d_ws;           // 100 floats of gate tables
  const int B = in_sizes[0] / NFEAT;   // 8192
  gate_prep<<<1, 16, 0, stream>>>(w, gt);
  qqk_kernel<<<B/4, NT, 0, stream>>>(x, gt, out);
}